// Round 3
// baseline (1298.361 us; speedup 1.0000x reference)
//
#include <hip/hip_runtime.h>

#define B_SZ 32768
#define SCALE_Q 0.17677669529663687f   // 1/sqrt(32)

// bf16 weight-region offsets (elements) inside wsW
#define OWQ 0
#define OWK 262144
#define OWV 524288
#define OWO 786432
#define OG1 1048576
#define OF1 1179648
#define OF2 2228224
#define OG1A 3276800
#define NW_TOT 3276800
#define NW_ALL 3342336

#define PX 264   // pitch (shorts) for xb_s/q_s/y_s/hf_s (b128-read buffers)
#define PK 266   // pitch (shorts) for k_s/v_s (u32-read buffers; odd bank stride)

typedef __attribute__((ext_vector_type(8))) short bf16x8;
typedef __attribute__((ext_vector_type(4))) float f32x4;

#define MFMA16(a,b,c) __builtin_amdgcn_mfma_f32_16x16x32_bf16((a),(b),(c),0,0,0)

__device__ __forceinline__ short f2b(float f){
  unsigned u = __float_as_uint(f);
  return (short)((u + 0x7FFFu + ((u >> 16) & 1u)) >> 16);
}
__device__ __forceinline__ float b2f(short s){
  return __uint_as_float(((unsigned)(unsigned short)s) << 16);
}
__device__ __forceinline__ float bflo(unsigned u){ return __uint_as_float(u << 16); }
__device__ __forceinline__ float bfhi(unsigned u){ return __uint_as_float(u & 0xFFFF0000u); }
__device__ __forceinline__ unsigned pack2(float a, float b){
  return (unsigned)(unsigned short)f2b(a) | (((unsigned)(unsigned short)f2b(b)) << 16);
}
__device__ __forceinline__ float gelu_f(float v){
  // tanh-form GELU as v*sigmoid(2z); |err| vs exact ~1e-3
  float z = 0.7978845608028654f*v + 0.03567740814183427f*v*v*v;
  z = fminf(fmaxf(z, -15.f), 15.f);
  return v / (1.f + __expf(-2.f*z));
}

// ---------------- K0: cast weights to bf16 in workspace ----------------
__global__ void k_cast_w(const float* __restrict__ Wq, const float* __restrict__ Wk,
                         const float* __restrict__ Wv, const float* __restrict__ Wo,
                         const float* __restrict__ g1w, const float* __restrict__ f1w,
                         const float* __restrict__ f2w, short* __restrict__ wsW){
  int i = blockIdx.x * 256 + threadIdx.x;
  if (i >= NW_TOT) return;
  const float* src; int off;
  if (i < OG1){ int r = i >> 18; off = i & 262143;
    src = (r == 0) ? Wq : (r == 1) ? Wk : (r == 2) ? Wv : Wo; }
  else if (i < OF1){ src = g1w; off = i - OG1; }
  else if (i < OF2){ src = f1w; off = i - OF1; }
  else { src = f2w; off = i - OF2; }
  wsW[i] = f2b(src[off]);
}

// ---------------- K0b: precompute G1A' = g1a@Wo (bf16) and g1b' = g1b + g1a@bo ----------------
__global__ void k_prep(const float* __restrict__ g1w, const float* __restrict__ g1b,
                       const float* __restrict__ Wo, const float* __restrict__ bo,
                       short* __restrict__ wsW, float* __restrict__ g1bp){
  const int m = blockIdx.x >> 3;
  const int h = ((blockIdx.x & 7) << 3) + (threadIdx.x >> 5);
  const int d = (threadIdx.x & 31) * 8;
  const float* g1a = g1w + ((size_t)m*64 + h)*512 + 256;
  const float* wom = Wo + (size_t)m*65536 + d;
  float acc[8];
#pragma unroll
  for (int j = 0; j < 8; ++j) acc[j] = 0.f;
  float bacc = 0.f;
  for (int o = 0; o < 256; ++o){
    float gv = g1a[o];
    const float4* w4 = (const float4*)(wom + (size_t)o*256);
    float4 wa = w4[0], wb = w4[1];
    acc[0] += gv*wa.x; acc[1] += gv*wa.y; acc[2] += gv*wa.z; acc[3] += gv*wa.w;
    acc[4] += gv*wb.x; acc[5] += gv*wb.y; acc[6] += gv*wb.z; acc[7] += gv*wb.w;
    bacc += gv * bo[m*256 + o];
  }
  short* dst = wsW + OG1A + ((size_t)m*64 + h)*256 + d;
#pragma unroll
  for (int j = 0; j < 8; ++j) dst[j] = f2b(acc[j]);
  if ((threadIdx.x & 31) == 0) g1bp[(size_t)m*64 + h] = bacc + g1b[m*64 + h];
}

// ---------------- K1: fused Q/K/V + attention + Wo + gate + LN ----------------
// 1024 threads (16 waves), 64-row tile (16 batches x 4 modalities), modality-major rows r=m*16+bl
__global__ __launch_bounds__(1024, 4)
void k_attn(const float* __restrict__ x, const short* __restrict__ wsW,
            const float* __restrict__ bq, const float* __restrict__ bk,
            const float* __restrict__ bv, const float* __restrict__ bo,
            const float* __restrict__ g1bp, const float* __restrict__ g2w,
            const float* __restrict__ g2b, const float* __restrict__ ln_g,
            const float* __restrict__ ln_b, short* __restrict__ wsY,
            float* __restrict__ gate_out)
{
  __shared__ __align__(16) short xb_s[64*PX];   // x tile (bf16)
  __shared__ __align__(16) short q_s [64*PX];   // Q (scaled) -> Oh
  __shared__ __align__(16) short k_s [64*PK];   // K -> attn_out
  __shared__ __align__(16) short v_s [64*PK];   // V
  __shared__ float gate_s[64];

  const int tid = threadIdx.x;
  const int b0  = blockIdx.x * 16;              // batch base
  const int w   = tid >> 6, lane = tid & 63;
  const int cl  = lane & 15, kb = lane >> 4;

  // ---- phase 0: stage x fp32 -> bf16 LDS (row r = m*16+bl) ----
  {
    int r = tid >> 4, s = tid & 15;
    int m = r >> 4, bl = r & 15;
    const float4* gp4 = (const float4*)(x + ((size_t)(b0 + bl)*4 + m) * 256);
    unsigned* dst = (unsigned*)&xb_s[r*PX];
#pragma unroll
    for (int j = 0; j < 4; ++j){
      float4 v = gp4[j*16 + s];
      int c = (j*16 + s)*2;
      dst[c]   = pack2(v.x, v.y);
      dst[c+1] = pack2(v.z, v.w);
    }
  }
  __syncthreads();

  // ---- phase 1: Q GEMM (wave: m=w&3, col-quarter oct=w>>2), scaled ----
  {
    const int m = w & 3, oct = w >> 2;
    const short* wq = wsW + OWQ + m*65536;
    f32x4 acc[4];
#pragma unroll
    for (int ct = 0; ct < 4; ++ct) acc[ct] = (f32x4){0.f,0.f,0.f,0.f};
    for (int kk = 0; kk < 8; ++kk){
      bf16x8 a = *(const bf16x8*)&xb_s[(m*16 + cl)*PX + kk*32 + kb*8];
#pragma unroll
      for (int ct = 0; ct < 4; ++ct){
        int col = oct*64 + ct*16 + cl;
        bf16x8 b = *(const bf16x8*)&wq[(size_t)col*256 + kk*32 + kb*8];
        acc[ct] = MFMA16(a, b, acc[ct]);
      }
    }
#pragma unroll
    for (int ct = 0; ct < 4; ++ct){
      int col = oct*64 + ct*16 + cl;
      float bs = bq[m*256 + col];
#pragma unroll
      for (int i = 0; i < 4; ++i)
        q_s[(m*16 + kb*4 + i)*PX + col] = f2b((acc[ct][i] + bs) * SCALE_Q);
    }
  }
  __syncthreads();

  // ---- phase 2: per query-modality mm: fused K+V GEMM -> scores/softmax/PV -> Oh in q_s ----
  for (int mm = 0; mm < 4; ++mm){
    {
      const int tgt = w >> 3, cw = w & 7;
      const short* Wm = wsW + (tgt ? OWV : OWK) + mm*65536;
      const float* bias = (tgt ? bv : bk) + mm*256;
      short* outb = tgt ? v_s : k_s;
      const int col0 = cw*32 + cl, col1 = cw*32 + 16 + cl;
      f32x4 acc0[4], acc1a[4];
#pragma unroll
      for (int rt = 0; rt < 4; ++rt){
        acc0[rt] = (f32x4){0.f,0.f,0.f,0.f};
        acc1a[rt] = (f32x4){0.f,0.f,0.f,0.f};
      }
      for (int kk = 0; kk < 8; ++kk){
        bf16x8 a[4];
#pragma unroll
        for (int rt = 0; rt < 4; ++rt)
          a[rt] = *(const bf16x8*)&xb_s[(rt*16 + cl)*PX + kk*32 + kb*8];
        bf16x8 b0v = *(const bf16x8*)&Wm[(size_t)col0*256 + kk*32 + kb*8];
        bf16x8 b1v = *(const bf16x8*)&Wm[(size_t)col1*256 + kk*32 + kb*8];
#pragma unroll
        for (int rt = 0; rt < 4; ++rt){
          acc0[rt]  = MFMA16(a[rt], b0v, acc0[rt]);
          acc1a[rt] = MFMA16(a[rt], b1v, acc1a[rt]);
        }
      }
      float bs0 = bias[col0], bs1 = bias[col1];
#pragma unroll
      for (int rt = 0; rt < 4; ++rt)
#pragma unroll
        for (int i = 0; i < 4; ++i){
          outb[(rt*16 + kb*4 + i)*PK + col0] = f2b(acc0[rt][i]  + bs0);
          outb[(rt*16 + kb*4 + i)*PK + col1] = f2b(acc1a[rt][i] + bs1);
        }
    }
    __syncthreads();
    if (tid < 512){  // scores + softmax + PV (wave-lockstep; Oh overwrites dead Q row)
      const int bl = tid >> 5, h = (tid >> 2) & 7, n = tid & 3;
      const int rot = ((bl & 1) + 2*h + 4*n) & 15;
      const short* qr = &q_s[(mm*16 + bl)*PX + h*32];
      const short* kr = &k_s[(n*16 + bl)*PK + h*32];
      float s = 0.f;
#pragma unroll
      for (int j = 0; j < 16; ++j){
        int jj = (j + rot) & 15;
        unsigned uq = *(const unsigned*)(qr + 2*jj);
        unsigned uk = *(const unsigned*)(kr + 2*jj);
        s += bflo(uq)*bflo(uk) + bfhi(uq)*bfhi(uk);
      }
      float mx = fmaxf(s, __shfl_xor(s, 1));
      mx = fmaxf(mx, __shfl_xor(mx, 2));
      float e = __expf(s - mx);
      float sum = e + __shfl_xor(e, 1);
      sum += __shfl_xor(sum, 2);
      float a = e / sum;
      float oh[8];
#pragma unroll
      for (int j = 0; j < 8; ++j) oh[j] = 0.f;
      const int lbase = lane & ~3;
#pragma unroll
      for (int np = 0; np < 4; ++np){
        float an = __shfl(a, lbase + np);
        const short* vr = &v_s[(np*16 + bl)*PK + h*32 + n*8];
#pragma unroll
        for (int j = 0; j < 4; ++j){
          unsigned u = *(const unsigned*)(vr + 2*j);
          oh[2*j]   += an * bflo(u);
          oh[2*j+1] += an * bfhi(u);
        }
      }
      unsigned* op = (unsigned*)&q_s[(mm*16 + bl)*PX + h*32 + n*8];
#pragma unroll
      for (int j = 0; j < 4; ++j) op[j] = pack2(oh[2*j], oh[2*j+1]);
    }
    __syncthreads();
  }

  // ---- phase 3: attn_out = Oh@Wo^T + bo -> k_s ; gate (waves 0-3, full K=512) ----
  {
    const int m = w & 3, oct = w >> 2;
    const short* wo = wsW + OWO + m*65536;
    f32x4 acc[4];
#pragma unroll
    for (int ct = 0; ct < 4; ++ct) acc[ct] = (f32x4){0.f,0.f,0.f,0.f};
    for (int kk = 0; kk < 8; ++kk){
      bf16x8 a = *(const bf16x8*)&q_s[(m*16 + cl)*PX + kk*32 + kb*8];
#pragma unroll
      for (int ct = 0; ct < 4; ++ct){
        int col = oct*64 + ct*16 + cl;
        bf16x8 b = *(const bf16x8*)&wo[(size_t)col*256 + kk*32 + kb*8];
        acc[ct] = MFMA16(a, b, acc[ct]);
      }
    }
#pragma unroll
    for (int ct = 0; ct < 4; ++ct){
      int col = oct*64 + ct*16 + cl;
      float bs = bo[m*256 + col];
#pragma unroll
      for (int i = 0; i < 4; ++i)
        k_s[(m*16 + kb*4 + i)*PK + col] = f2b(acc[ct][i] + bs);
    }
  }
  if (w < 4){
    const int m = w;
    const short* g1x = wsW + OG1 + m*32768;    // [64][512], x-part cols 0..255
    const short* g1a = wsW + OG1A + m*16384;   // [64][256], Oh-part (pre-multiplied by Wo)
    f32x4 acc[4];
#pragma unroll
    for (int ct = 0; ct < 4; ++ct) acc[ct] = (f32x4){0.f,0.f,0.f,0.f};
    for (int kk = 0; kk < 8; ++kk){
      bf16x8 a = *(const bf16x8*)&xb_s[(m*16 + cl)*PX + kk*32 + kb*8];
#pragma unroll
      for (int ct = 0; ct < 4; ++ct){
        int hc = ct*16 + cl;
        bf16x8 b = *(const bf16x8*)&g1x[(size_t)hc*512 + kk*32 + kb*8];
        acc[ct] = MFMA16(a, b, acc[ct]);
      }
    }
    for (int kk = 0; kk < 8; ++kk){
      bf16x8 a = *(const bf16x8*)&q_s[(m*16 + cl)*PX + kk*32 + kb*8];
#pragma unroll
      for (int ct = 0; ct < 4; ++ct){
        int hc = ct*16 + cl;
        bf16x8 b = *(const bf16x8*)&g1a[(size_t)hc*256 + kk*32 + kb*8];
        acc[ct] = MFMA16(a, b, acc[ct]);
      }
    }
    float p[4] = {0.f,0.f,0.f,0.f};
#pragma unroll
    for (int ct = 0; ct < 4; ++ct){
      int hc = ct*16 + cl;
      float b1 = g1bp[m*64 + hc], w2 = g2w[m*64 + hc];
#pragma unroll
      for (int i = 0; i < 4; ++i) p[i] += tanhf(acc[ct][i] + b1) * w2;
    }
#pragma unroll
    for (int i = 0; i < 4; ++i){
      p[i] += __shfl_xor(p[i], 1);
      p[i] += __shfl_xor(p[i], 2);
      p[i] += __shfl_xor(p[i], 4);
      p[i] += __shfl_xor(p[i], 8);
    }
    if (cl == 0){
#pragma unroll
      for (int i = 0; i < 4; ++i){
        int bl = kb*4 + i;
        float g = 1.f / (1.f + __expf(-(p[i] + g2b[m])));
        gate_s[m*16 + bl] = g;
        gate_out[(size_t)(b0 + bl)*4 + m] = g;
      }
    }
  }
  __syncthreads();

  // ---- phase 4: residual + LayerNorm -> wsY (bf16) ----
  {
    const int r = tid >> 4, sg = tid & 15;
    const int m = r >> 4, bl = r & 15;
    const float g = gate_s[r];
    const short* xr = &xb_s[r*PX];
    const short* ar = &k_s[r*PK];
    float rv[16];
    float sum = 0.f, sq = 0.f;
#pragma unroll
    for (int j = 0; j < 8; ++j){
      int colh = sg*16 + 2*j;
      unsigned ux = *(const unsigned*)(xr + colh);
      unsigned ua = *(const unsigned*)(ar + colh);
      float v0 = bflo(ux) + g*bflo(ua);
      float v1 = bfhi(ux) + g*bfhi(ua);
      rv[2*j] = v0; rv[2*j+1] = v1;
      sum += v0 + v1; sq += v0*v0 + v1*v1;
    }
#pragma unroll
    for (int o = 1; o < 16; o <<= 1){
      sum += __shfl_xor(sum, o);
      sq  += __shfl_xor(sq, o);
    }
    float mu  = sum * (1.f/256.f);
    float var = sq * (1.f/256.f) - mu*mu;
    float rstd = rsqrtf(var + 1e-5f);
    const float* lg = ln_g + m*256 + sg*16;
    const float* lb = ln_b + m*256 + sg*16;
    unsigned* yp = (unsigned*)(wsY + ((size_t)(b0 + bl)*4 + m)*256 + sg*16);
#pragma unroll
    for (int j = 0; j < 8; ++j){
      float y0 = (rv[2*j]   - mu)*rstd*lg[2*j]   + lb[2*j];
      float y1 = (rv[2*j+1] - mu)*rstd*lg[2*j+1] + lb[2*j+1];
      yp[j] = pack2(y0, y1);
    }
  }
}

// ---------------- K2: fused FeedForward (f1 + GELU + f2 + residual), 64-row tile ----------------
__global__ __launch_bounds__(512, 4)
void k_ff(const short* __restrict__ wsY, const short* __restrict__ wsW,
          const float* __restrict__ f1bias, const float* __restrict__ f2bias,
          float* __restrict__ out)
{
  __shared__ __align__(16) short y_s [64*PX];
  __shared__ __align__(16) short hf_s[64*PX];
  const int tid = threadIdx.x;
  const int m  = blockIdx.x >> 9;
  const int b0 = (blockIdx.x & 511) * 64;
  const int w = tid >> 6, lane = tid & 63, cl = lane & 15, kb = lane >> 4;

  {  // stage y tile (modality m, rows stride-4 in global)
    int r = tid >> 3, s = tid & 7;
    const short* src = wsY + ((size_t)(b0 + r)*4 + m)*256 + s*32;
    short* dst = &y_s[r*PX + s*32];
#pragma unroll
    for (int q = 0; q < 4; ++q)
      *(bf16x8*)(dst + q*8) = *(const bf16x8*)(src + q*8);
  }
  __syncthreads();

  f32x4 accO[4][2];
#pragma unroll
  for (int rt = 0; rt < 4; ++rt){
    accO[rt][0] = (f32x4){0.f,0.f,0.f,0.f};
    accO[rt][1] = (f32x4){0.f,0.f,0.f,0.f};
  }

  for (int ch = 0; ch < 4; ++ch){
    f32x4 acc1[4][2];
#pragma unroll
    for (int rt = 0; rt < 4; ++rt){
      acc1[rt][0] = (f32x4){0.f,0.f,0.f,0.f};
      acc1[rt][1] = (f32x4){0.f,0.f,0.f,0.f};
    }
    for (int kk = 0; kk < 8; ++kk){
      bf16x8 a[4];
#pragma unroll
      for (int rt = 0; rt < 4; ++rt)
        a[rt] = *(const bf16x8*)&y_s[(rt*16 + cl)*PX + kk*32 + kb*8];
#pragma unroll
      for (int c = 0; c < 2; ++c){
        size_t ncol = (size_t)(ch*256 + w*32 + c*16 + cl);
        bf16x8 b = *(const bf16x8*)&wsW[OF1 + (size_t)m*262144 + ncol*256 + kk*32 + kb*8];
#pragma unroll
        for (int rt = 0; rt < 4; ++rt)
          acc1[rt][c] = MFMA16(a[rt], b, acc1[rt][c]);
      }
    }
#pragma unroll
    for (int c = 0; c < 2; ++c){
      int ncl = w*32 + c*16 + cl;
      float bs = f1bias[m*1024 + ch*256 + ncl];
#pragma unroll
      for (int rt = 0; rt < 4; ++rt)
#pragma unroll
        for (int i = 0; i < 4; ++i)
          hf_s[(rt*16 + kb*4 + i)*PX + ncl] = f2b(gelu_f(acc1[rt][c][i] + bs));
    }
    __syncthreads();
    for (int kk = 0; kk < 8; ++kk){
      bf16x8 a[4];
#pragma unroll
      for (int rt = 0; rt < 4; ++rt)
        a[rt] = *(const bf16x8*)&hf_s[(rt*16 + cl)*PX + kk*32 + kb*8];
#pragma unroll
      for (int c = 0; c < 2; ++c){
        size_t ocol = (size_t)(w*32 + c*16 + cl);
        bf16x8 b = *(const bf16x8*)&wsW[OF2 + (size_t)m*262144 + ocol*1024 + ch*256 + kk*32 + kb*8];
#pragma unroll
        for (int rt = 0; rt < 4; ++rt)
          accO[rt][c] = MFMA16(a[rt], b, accO[rt][c]);
      }
    }
    __syncthreads();
  }

  // epilogue: updated = y + ff + f2bias
#pragma unroll
  for (int c = 0; c < 2; ++c){
    int col = w*32 + c*16 + cl;
    float bs = f2bias[m*256 + col];
#pragma unroll
    for (int rt = 0; rt < 4; ++rt)
#pragma unroll
      for (int i = 0; i < 4; ++i){
        int row = rt*16 + kb*4 + i;
        out[((size_t)(b0 + row)*4 + m)*256 + col] = accO[rt][c][i] + bs + b2f(y_s[row*PX + col]);
      }
  }
}

extern "C" void kernel_launch(void* const* d_in, const int* in_sizes, int n_in,
                              void* d_out, int out_size, void* d_ws, size_t ws_size,
                              hipStream_t stream){
  const float* x    = (const float*)d_in[0];
  const float* Wq   = (const float*)d_in[1];
  const float* bq   = (const float*)d_in[2];
  const float* Wk   = (const float*)d_in[3];
  const float* bk   = (const float*)d_in[4];
  const float* Wv   = (const float*)d_in[5];
  const float* bv   = (const float*)d_in[6];
  const float* Wo   = (const float*)d_in[7];
  const float* bo   = (const float*)d_in[8];
  const float* g1w  = (const float*)d_in[9];
  const float* g1b  = (const float*)d_in[10];
  const float* g2w  = (const float*)d_in[11];
  const float* g2b  = (const float*)d_in[12];
  const float* ln_g = (const float*)d_in[13];
  const float* ln_b = (const float*)d_in[14];
  const float* f1w  = (const float*)d_in[15];
  const float* f1b  = (const float*)d_in[16];
  const float* f2w  = (const float*)d_in[17];
  const float* f2bb = (const float*)d_in[18];

  float* out      = (float*)d_out;
  float* gate_out = out + (size_t)B_SZ * 4 * 256;

  short* wsY = (short*)d_ws;
  short* wsW = (short*)d_ws + (size_t)B_SZ * 4 * 256;
  float* g1bp = (float*)(wsW + NW_ALL);

  hipLaunchKernelGGL(k_cast_w, dim3((NW_TOT + 255) / 256), dim3(256), 0, stream,
                     Wq, Wk, Wv, Wo, g1w, f1w, f2w, wsW);
  hipLaunchKernelGGL(k_prep, dim3(32), dim3(256), 0, stream,
                     g1w, g1b, Wo, bo, wsW, g1bp);
  hipLaunchKernelGGL(k_attn, dim3(B_SZ / 16), dim3(1024), 0, stream,
                     x, wsW, bq, bk, bv, bo, g1bp, g2w, g2b, ln_g, ln_b, wsY, gate_out);
  hipLaunchKernelGGL(k_ff, dim3(4 * (B_SZ / 64)), dim3(512), 0, stream,
                     wsY, wsW, f1b, f2bb, out);
}